// Round 14
// baseline (90.035 us; speedup 1.0000x reference)
//
#include <hip/hip_runtime.h>
#include <hip/hip_bf16.h>
#include <stdint.h>

typedef __attribute__((ext_vector_type(8))) short bf16x8;
typedef __attribute__((ext_vector_type(4))) float f32x4;
typedef __attribute__((ext_vector_type(4))) unsigned int u32x4;

__device__ __forceinline__ float u2f(unsigned int u) {
  union { unsigned int i; float f; } c; c.i = u; return c.f;
}
__device__ __forceinline__ unsigned int f2b(float f) {
  union { float f; unsigned int i; } c; c.f = f;
  unsigned int x = c.i;
  return (x + 0x7fffu + ((x >> 16) & 1u)) >> 16;  // RNE to bf16
}

// ================= prep kernel (= R13) =================
__global__ __launch_bounds__(256) void k_prep(
    const float* __restrict__ shape, const float* __restrict__ w_off,
    const float* __restrict__ x, const float* __restrict__ wd,
    char* __restrict__ desc, unsigned short* __restrict__ xt,
    unsigned short* __restrict__ wp) {
  __shared__ float tile[64][65];
  int bid = blockIdx.x;
  int t = threadIdx.x;
  if (bid < 576) {
    // ---- descriptors (16B): {u32 idx01 (two u16 pos idx), u32 idx23, u32 w01, u32 w23} ----
    int band = bid & 3;
    int rem = bid >> 2;                 // = b*36 + g*9 + kk
    int b = rem / 36, r2 = rem % 36, g = r2 / 9, kk = r2 % 9;
    int ky = kk / 3, kx = kk - ky * 3;
    int ocy = g * 18 + kk * 2;
    float wy[18], wx[18];
#pragma unroll
    for (int i = 0; i < 18; ++i) { wy[i] = w_off[ocy * 18 + i]; wx[i] = w_off[(ocy + 1) * 18 + i]; }
    const float* sp = shape + (size_t)b * 2 * 4096;
    char* dp = desc + (size_t)rem * 4096 * 16;
#pragma unroll
    for (int e = 0; e < 4; ++e) {
      int p = band * 1024 + t * 4 + e;
      int y = p >> 6, xx0 = p & 63;
      float dy = 0.f, dx = 0.f;
#pragma unroll
      for (int ic = 0; ic < 2; ++ic)
#pragma unroll
        for (int kyy = 0; kyy < 3; ++kyy) {
          int yy = y + kyy - 1;
          if (yy < 0 || yy > 63) continue;
#pragma unroll
          for (int kxx = 0; kxx < 3; ++kxx) {
            int xx = xx0 + kxx - 1;
            if (xx < 0 || xx > 63) continue;
            float sv = sp[ic * 4096 + yy * 64 + xx];
            dy += sv * wy[ic * 9 + kyy * 3 + kxx];
            dx += sv * wx[ic * 9 + kyy * 3 + kxx];
          }
        }
      float sy = dy + (float)(y + ky - 1);
      float sx = dx + (float)(xx0 + kx - 1);
      float fy = floorf(sy), fx = floorf(sx);
      float ly = sy - fy, lx = sx - fx;
      int y0 = (int)fy, x0 = (int)fx;
      float vy0 = (y0 >= 0 && y0 <= 63) ? 1.f : 0.f;
      float vy1 = (y0 >= -1 && y0 <= 62) ? 1.f : 0.f;
      float vx0 = (x0 >= 0 && x0 <= 63) ? 1.f : 0.f;
      float vx1 = (x0 >= -1 && x0 <= 62) ? 1.f : 0.f;
      float w00 = (1.f - ly) * (1.f - lx) * vy0 * vx0;
      float w01 = (1.f - ly) * lx * vy0 * vx1;
      float w10 = ly * (1.f - lx) * vy1 * vx0;
      float w11 = ly * lx * vy1 * vx1;
      unsigned int yc0 = (unsigned int)min(max(y0, 0), 63);
      unsigned int yc1 = (unsigned int)min(max(y0 + 1, 0), 63);
      unsigned int xc0 = (unsigned int)min(max(x0, 0), 63);
      unsigned int xc1 = (unsigned int)min(max(x0 + 1, 0), 63);
      u32x4 d;
      d[0] = (yc0 * 64 + xc0) | ((yc0 * 64 + xc1) << 16);
      d[1] = (yc1 * 64 + xc0) | ((yc1 * 64 + xc1) << 16);
      d[2] = f2b(w00) | (f2b(w01) << 16);
      d[3] = f2b(w10) | (f2b(w11) << 16);
      *(u32x4*)(dp + (size_t)p * 16) = d;
    }
  } else if (bid < 1600) {
    // ---- transpose ----
    int id = bid - 576;
    int b = id >> 8, ct = (id >> 6) & 3, pt = id & 63;
    int c0 = ct * 64, p0 = pt * 64;
#pragma unroll
    for (int i = 0; i < 4; ++i) {
      int row = (t >> 4) + i * 16;
      int seg = t & 15;
      float4 v = *(const float4*)&x[(size_t)(b * 256 + c0 + row) * 4096 + p0 + seg * 4];
      tile[row][seg * 4 + 0] = v.x;
      tile[row][seg * 4 + 1] = v.y;
      tile[row][seg * 4 + 2] = v.z;
      tile[row][seg * 4 + 3] = v.w;
    }
    __syncthreads();
    {
      int pl = t >> 2;
      int cs = (t & 3) * 16;
      unsigned int wbuf[8];
#pragma unroll
      for (int j = 0; j < 8; ++j)
        wbuf[j] = f2b(tile[cs + 2 * j][pl]) | (f2b(tile[cs + 2 * j + 1][pl]) << 16);
      unsigned short* dst = xt + (size_t)(b * 4096 + p0 + pl) * 256 + c0 + cs;
      *(u32x4*)(dst) = *(u32x4*)&wbuf[0];
      *(u32x4*)(dst + 8) = *(u32x4*)&wbuf[4];
    }
  } else {
    // ---- weight pack (SWIZZLED for linear global_load_lds staging) ----
    int id = (bid - 1600) * 256 + t;
    int m = id >> 8, ci = id & 255;
    int g = ci >> 6, c = ci & 63;
    int cs = c ^ ((m & 7) << 3);
    const float* src = wd + (size_t)(m * 256 + ci) * 9;
    float v[9];
#pragma unroll
    for (int kk = 0; kk < 9; ++kk) v[kk] = src[kk];
#pragma unroll
    for (int kk = 0; kk < 9; ++kk)
      wp[(size_t)(kk * 4 + g) * 16384 + m * 64 + cs] = (unsigned short)f2b(v[kk]);
  }
}

// ================= main fused kernel =================
// grid 1024: (b, y, xq); 256 thr (4 waves); tile M=256 x N=16 (dedup'd sampling)
// -> EXACTLY 4 blocks/CU (LDS 36KB), 16 waves/CU in 4 independent barrier groups.
// A: SINGLE 32KB LDS buffer via global_load_lds (pre-swizzled); B dbuf 2x2KB.
// R13's counted-drain schedule: 2 barriers/phase; bar2 = lgkm + vmcnt(5) drains the
// 8 stage loads only; corners(c+2)+desc(c+3) stay in flight across both barriers.
struct CSet { uint2 v0, v1, v2, v3; unsigned int w01, w23; };

#define DESC_LD(c, dv) do { \
    dv = *(const u32x4*)(descb + (size_t)(((c) & 3) * 9 + ((c) >> 2)) * 65536); \
  } while (0)

#define CORNERS(S, dv, cc) do { \
    unsigned int base_ = (unsigned int)(((cc) & 3) << 7) + cb8; \
    (S).v0 = *(const uint2*)(xtbB + (((dv)[0] & 0xffffu) << 9) + base_); \
    (S).v1 = *(const uint2*)(xtbB + (((dv)[0] >> 16) << 9) + base_); \
    (S).v2 = *(const uint2*)(xtbB + (((dv)[1] & 0xffffu) << 9) + base_); \
    (S).v3 = *(const uint2*)(xtbB + (((dv)[1] >> 16) << 9) + base_); \
    (S).w01 = (dv)[2]; \
    (S).w23 = (dv)[3]; \
  } while (0)

#define BLEND(S, bbuf) do { \
    float w0_ = u2f((S).w01 << 16), w1_ = u2f((S).w01 & 0xffff0000u); \
    float w2_ = u2f((S).w23 << 16), w3_ = u2f((S).w23 & 0xffff0000u); \
    uint2 o_; \
    { \
      float lo_ = w0_ * u2f((S).v0.x << 16) + w1_ * u2f((S).v1.x << 16) \
                + w2_ * u2f((S).v2.x << 16) + w3_ * u2f((S).v3.x << 16); \
      float hi_ = w0_ * u2f((S).v0.x & 0xffff0000u) + w1_ * u2f((S).v1.x & 0xffff0000u) \
                + w2_ * u2f((S).v2.x & 0xffff0000u) + w3_ * u2f((S).v3.x & 0xffff0000u); \
      o_.x = f2b(lo_) | (f2b(hi_) << 16); \
    } \
    { \
      float lo_ = w0_ * u2f((S).v0.y << 16) + w1_ * u2f((S).v1.y << 16) \
                + w2_ * u2f((S).v2.y << 16) + w3_ * u2f((S).v3.y << 16); \
      float hi_ = w0_ * u2f((S).v0.y & 0xffff0000u) + w1_ * u2f((S).v1.y & 0xffff0000u) \
                + w2_ * u2f((S).v2.y & 0xffff0000u) + w3_ * u2f((S).v3.y & 0xffff0000u); \
      o_.y = f2b(lo_) | (f2b(hi_) << 16); \
    } \
    *(uint2*)((bbuf) + bwr) = o_; \
  } while (0)

// stage A chunk (32KB): 256 thr x 8 x 16B linear copy of pre-swizzled image
#define STAGE_A(c) do { \
    const unsigned short* asrc_ = wp + (size_t)(c) * 16384 + t * 8; \
    _Pragma("unroll") for (int i_ = 0; i_ < 8; ++i_) \
      __builtin_amdgcn_global_load_lds( \
          (const __attribute__((address_space(1))) unsigned int*)(asrc_ + i_ * 2048), \
          (__attribute__((address_space(3))) unsigned int*)(ldsA + t * 16 + i_ * 4096), \
          16, 0, 0); \
  } while (0)

// MFMA: wave tile 64x16; per k-step 1 B-frag + 4 A-frags
#define MFMA_STEP(bbuf) do { \
    _Pragma("unroll") for (int ks_ = 0; ks_ < 2; ++ks_) { \
      int kb_ = ks_ * 64 + kq; \
      bf16x8 bf_ = *(const bf16x8*)((bbuf) + lm * 128 + (kb_ ^ swz)); \
      bf16x8 a0_ = *(const bf16x8*)(ldsA + (wbase + lm) * 128 + (kb_ ^ swz)); \
      bf16x8 a1_ = *(const bf16x8*)(ldsA + (wbase + 16 + lm) * 128 + (kb_ ^ swz)); \
      bf16x8 a2_ = *(const bf16x8*)(ldsA + (wbase + 32 + lm) * 128 + (kb_ ^ swz)); \
      bf16x8 a3_ = *(const bf16x8*)(ldsA + (wbase + 48 + lm) * 128 + (kb_ ^ swz)); \
      acc0 = __builtin_amdgcn_mfma_f32_16x16x32_bf16(a0_, bf_, acc0, 0, 0, 0); \
      acc1 = __builtin_amdgcn_mfma_f32_16x16x32_bf16(a1_, bf_, acc1, 0, 0, 0); \
      acc2 = __builtin_amdgcn_mfma_f32_16x16x32_bf16(a2_, bf_, acc2, 0, 0, 0); \
      acc3 = __builtin_amdgcn_mfma_f32_16x16x32_bf16(a3_, bf_, acc3, 0, 0, 0); \
    } \
  } while (0)

// Phase(c): MFMA A(c)xB(c); bar1 (lgkm: A/B reads done); stage A(c+1) (overwrite);
// corners(c+2); desc(c+3); blend corners(c+1)->B(c+1); bar2 (lgkm + vmcnt(5): stage only).
#define PHASE(c, Bcur, Bnext, Scur, Snext, dvU, dvF) do { \
    MFMA_STEP(Bcur); \
    asm volatile("s_waitcnt lgkmcnt(0)" ::: "memory"); \
    __builtin_amdgcn_s_barrier(); \
    { int ca_ = (c) + 1 < 36 ? (c) + 1 : 35; STAGE_A(ca_); } \
    { int cc_ = (c) + 2 < 36 ? (c) + 2 : 35; CORNERS(Snext, dvU, cc_); } \
    { int cd_ = (c) + 3 < 36 ? (c) + 3 : 35; DESC_LD(cd_, dvF); } \
    BLEND(Scur, Bnext); \
    asm volatile("s_waitcnt lgkmcnt(0)" ::: "memory"); \
    asm volatile("s_waitcnt vmcnt(5)" ::: "memory"); \
    __builtin_amdgcn_s_barrier(); \
  } while (0)

__global__ __launch_bounds__(256, 4) void k_deform_main(
    const unsigned short* __restrict__ xt, const unsigned short* __restrict__ wp,
    const char* __restrict__ desc, float* __restrict__ out) {
  __shared__ __align__(16) char lds[36864];  // A: 32KB single; B0,B1: 2KB each
  const int t = threadIdx.x;
  const int l = t & 63;
  const int wid = t >> 6;                    // 0..3: 64-row m-slice
  const int wbase = wid * 64;

  int orig = blockIdx.x;
  int bid = (orig & 7) * 128 + (orig >> 3);  // XCD chunked swizzle (1024%8==0)
  const int xq = bid & 3;
  const int rowid = bid >> 2;                // 0..255
  const int b = rowid >> 6;
  const int y = rowid & 63;

  const int p = t >> 4;                      // local position 0..15
  const int cq = t & 15;                     // channel quad (4 ch)
  const unsigned int cb8 = cq * 8;
  const int bwr = p * 128 + ((cq * 8) ^ ((p & 7) << 4));

  const int lm = l & 15;
  const int kq = (l >> 4) << 4;
  const int swz = (lm & 7) << 4;

  f32x4 acc0 = {}, acc1 = {}, acc2 = {}, acc3 = {};

  const char* descb = desc + (size_t)(b * 36 * 4096 + y * 64 + xq * 16 + p) * 16;
  const char* xtbB = (const char*)(xt + (size_t)b * 4096 * 256);

  char* ldsA = lds;
  char* ldsB0 = lds + 32768;
  char* ldsB1 = lds + 34816;

  CSet SE, SO;
  u32x4 dvA, dvB;

  // ---- prologue: A(0) staged+drained; B(0) built; SE = corners(1) in flight; dvA = desc(2) ----
  {
    u32x4 d0, d1;
    DESC_LD(0, d0);
    DESC_LD(1, d1);
    DESC_LD(2, dvA);
    STAGE_A(0);
    CSet St;
    CORNERS(St, d0, 0);
    BLEND(St, ldsB0);                 // implicit full drain (corners(0) are newest)
    CORNERS(SE, d1, 1);               // stays in flight across the barrier
    asm volatile("s_waitcnt lgkmcnt(0)" ::: "memory");
    asm volatile("s_waitcnt vmcnt(4)" ::: "memory");   // keep corners(1) only
    __builtin_amdgcn_s_barrier();
  }

  // ---- 36 phases, 2-phase rotation (B buf, corner set, desc slot) ----
  for (int pr = 0; pr < 18; ++pr) {
    const int c = pr * 2;
    PHASE(c,     ldsB0, ldsB1, SE, SO, dvA, dvB);
    PHASE(c + 1, ldsB1, ldsB0, SO, SE, dvB, dvA);
  }

  // ---- epilogue: ReLU + fp32 store ----
  const int lm4 = (l >> 4) << 2;
  float* ob = out + (size_t)(b * 256 + wbase) * 4096 + y * 64 + xq * 16 + lm;
#pragma unroll
  for (int r = 0; r < 4; ++r) {
    ob[(size_t)(lm4 + r) * 4096] = fmaxf(acc0[r], 0.f);
    ob[(size_t)(16 + lm4 + r) * 4096] = fmaxf(acc1[r], 0.f);
    ob[(size_t)(32 + lm4 + r) * 4096] = fmaxf(acc2[r], 0.f);
    ob[(size_t)(48 + lm4 + r) * 4096] = fmaxf(acc3[r], 0.f);
  }
}

extern "C" void kernel_launch(void* const* d_in, const int* in_sizes, int n_in,
                              void* d_out, int out_size, void* d_ws, size_t ws_size,
                              hipStream_t stream) {
  const float* x     = (const float*)d_in[0];
  const float* shape = (const float*)d_in[1];
  const float* w_off = (const float*)d_in[2];
  const float* w_def = (const float*)d_in[3];
  float* out = (float*)d_out;
  char* ws = (char*)d_ws;

  char* desc          = ws;                                          // 9,437,184 B
  unsigned short* xt  = (unsigned short*)(ws + 9437184);             // 8,388,608 B
  unsigned short* wpk = (unsigned short*)(ws + 9437184 + 8388608);   // 1,179,648 B

  k_prep<<<1856, 256, 0, stream>>>(shape, w_off, x, w_def, desc, xt, wpk);
  k_deform_main<<<1024, 256, 0, stream>>>(xt, wpk, desc, out);
}

// Round 15
// 73.590 us; speedup vs baseline: 1.2235x; 1.2235x over previous
//
#include <hip/hip_runtime.h>
#include <hip/hip_bf16.h>
#include <stdint.h>

typedef __attribute__((ext_vector_type(8))) short bf16x8;
typedef __attribute__((ext_vector_type(4))) float f32x4;
typedef __attribute__((ext_vector_type(4))) unsigned int u32x4;

__device__ __forceinline__ float u2f(unsigned int u) {
  union { unsigned int i; float f; } c; c.i = u; return c.f;
}
__device__ __forceinline__ unsigned int f2b(float f) {
  union { float f; unsigned int i; } c; c.f = f;
  unsigned int x = c.i;
  return (x + 0x7fffu + ((x >> 16) & 1u)) >> 16;  // RNE to bf16
}

// ================= prep kernel (= R10/R13) =================
__global__ __launch_bounds__(256) void k_prep(
    const float* __restrict__ shape, const float* __restrict__ w_off,
    const float* __restrict__ x, const float* __restrict__ wd,
    char* __restrict__ desc, unsigned short* __restrict__ xt,
    unsigned short* __restrict__ wp) {
  __shared__ float tile[64][65];
  int bid = blockIdx.x;
  int t = threadIdx.x;
  if (bid < 576) {
    // ---- descriptors (16B): {u32 idx01 (two u16 pos idx), u32 idx23, u32 w01, u32 w23} ----
    int band = bid & 3;
    int rem = bid >> 2;                 // = b*36 + g*9 + kk
    int b = rem / 36, r2 = rem % 36, g = r2 / 9, kk = r2 % 9;
    int ky = kk / 3, kx = kk - ky * 3;
    int ocy = g * 18 + kk * 2;
    float wy[18], wx[18];
#pragma unroll
    for (int i = 0; i < 18; ++i) { wy[i] = w_off[ocy * 18 + i]; wx[i] = w_off[(ocy + 1) * 18 + i]; }
    const float* sp = shape + (size_t)b * 2 * 4096;
    char* dp = desc + (size_t)rem * 4096 * 16;
#pragma unroll
    for (int e = 0; e < 4; ++e) {
      int p = band * 1024 + t * 4 + e;
      int y = p >> 6, xx0 = p & 63;
      float dy = 0.f, dx = 0.f;
#pragma unroll
      for (int ic = 0; ic < 2; ++ic)
#pragma unroll
        for (int kyy = 0; kyy < 3; ++kyy) {
          int yy = y + kyy - 1;
          if (yy < 0 || yy > 63) continue;
#pragma unroll
          for (int kxx = 0; kxx < 3; ++kxx) {
            int xx = xx0 + kxx - 1;
            if (xx < 0 || xx > 63) continue;
            float sv = sp[ic * 4096 + yy * 64 + xx];
            dy += sv * wy[ic * 9 + kyy * 3 + kxx];
            dx += sv * wx[ic * 9 + kyy * 3 + kxx];
          }
        }
      float sy = dy + (float)(y + ky - 1);
      float sx = dx + (float)(xx0 + kx - 1);
      float fy = floorf(sy), fx = floorf(sx);
      float ly = sy - fy, lx = sx - fx;
      int y0 = (int)fy, x0 = (int)fx;
      float vy0 = (y0 >= 0 && y0 <= 63) ? 1.f : 0.f;
      float vy1 = (y0 >= -1 && y0 <= 62) ? 1.f : 0.f;
      float vx0 = (x0 >= 0 && x0 <= 63) ? 1.f : 0.f;
      float vx1 = (x0 >= -1 && x0 <= 62) ? 1.f : 0.f;
      float w00 = (1.f - ly) * (1.f - lx) * vy0 * vx0;
      float w01 = (1.f - ly) * lx * vy0 * vx1;
      float w10 = ly * (1.f - lx) * vy1 * vx0;
      float w11 = ly * lx * vy1 * vx1;
      unsigned int yc0 = (unsigned int)min(max(y0, 0), 63);
      unsigned int yc1 = (unsigned int)min(max(y0 + 1, 0), 63);
      unsigned int xc0 = (unsigned int)min(max(x0, 0), 63);
      unsigned int xc1 = (unsigned int)min(max(x0 + 1, 0), 63);
      u32x4 d;
      d[0] = (yc0 * 64 + xc0) | ((yc0 * 64 + xc1) << 16);
      d[1] = (yc1 * 64 + xc0) | ((yc1 * 64 + xc1) << 16);
      d[2] = f2b(w00) | (f2b(w01) << 16);
      d[3] = f2b(w10) | (f2b(w11) << 16);
      *(u32x4*)(dp + (size_t)p * 16) = d;
    }
  } else if (bid < 1600) {
    // ---- transpose ----
    int id = bid - 576;
    int b = id >> 8, ct = (id >> 6) & 3, pt = id & 63;
    int c0 = ct * 64, p0 = pt * 64;
#pragma unroll
    for (int i = 0; i < 4; ++i) {
      int row = (t >> 4) + i * 16;
      int seg = t & 15;
      float4 v = *(const float4*)&x[(size_t)(b * 256 + c0 + row) * 4096 + p0 + seg * 4];
      tile[row][seg * 4 + 0] = v.x;
      tile[row][seg * 4 + 1] = v.y;
      tile[row][seg * 4 + 2] = v.z;
      tile[row][seg * 4 + 3] = v.w;
    }
    __syncthreads();
    {
      int pl = t >> 2;
      int cs = (t & 3) * 16;
      unsigned int wbuf[8];
#pragma unroll
      for (int j = 0; j < 8; ++j)
        wbuf[j] = f2b(tile[cs + 2 * j][pl]) | (f2b(tile[cs + 2 * j + 1][pl]) << 16);
      unsigned short* dst = xt + (size_t)(b * 4096 + p0 + pl) * 256 + c0 + cs;
      *(u32x4*)(dst) = *(u32x4*)&wbuf[0];
      *(u32x4*)(dst + 8) = *(u32x4*)&wbuf[4];
    }
  } else {
    // ---- weight pack (SWIZZLED for linear global_load_lds staging) ----
    int id = (bid - 1600) * 256 + t;
    int m = id >> 8, ci = id & 255;
    int g = ci >> 6, c = ci & 63;
    int cs = c ^ ((m & 7) << 3);
    const float* src = wd + (size_t)(m * 256 + ci) * 9;
    float v[9];
#pragma unroll
    for (int kk = 0; kk < 9; ++kk) v[kk] = src[kk];
#pragma unroll
    for (int kk = 0; kk < 9; ++kk)
      wp[(size_t)(kk * 4 + g) * 16384 + m * 64 + cs] = (unsigned short)f2b(v[kk]);
  }
}

// ================= main fused kernel =================
// R10 structure, PAIRED-CHUNK phases (2 K-chunks per barrier pair -> 18 phases).
// grid 512: (b,y,xh); 512 thr (8 waves); tile M=256 x N=32.
// A: LDS dbuf 2x32KB (even/odd chunk) via global_load_lds (pre-swizzled); B dbuf 2x4KB.
// Per phase: MFMA both chunks; bar1(lgkm); stage next pair (8 vmem); corners pair+2 (8);
// desc pair+3 (2); blend pair+1 -> B; bar2(lgkm + vmcnt(10): drains stage only).
struct CSet { uint2 v0, v1, v2, v3; unsigned int w01, w23; };

#define DESC_LD(c, dv) do { \
    dv = *(const u32x4*)(descb + (size_t)(((c) & 3) * 9 + ((c) >> 2)) * 65536); \
  } while (0)

#define CORNERS(S, dv, cc) do { \
    unsigned int base_ = (unsigned int)(((cc) & 3) << 7) + cb8; \
    (S).v0 = *(const uint2*)(xtbB + (((dv)[0] & 0xffffu) << 9) + base_); \
    (S).v1 = *(const uint2*)(xtbB + (((dv)[0] >> 16) << 9) + base_); \
    (S).v2 = *(const uint2*)(xtbB + (((dv)[1] & 0xffffu) << 9) + base_); \
    (S).v3 = *(const uint2*)(xtbB + (((dv)[1] >> 16) << 9) + base_); \
    (S).w01 = (dv)[2]; \
    (S).w23 = (dv)[3]; \
  } while (0)

#define BLEND(S, bbuf) do { \
    float w0_ = u2f((S).w01 << 16), w1_ = u2f((S).w01 & 0xffff0000u); \
    float w2_ = u2f((S).w23 << 16), w3_ = u2f((S).w23 & 0xffff0000u); \
    uint2 o_; \
    { \
      float lo_ = w0_ * u2f((S).v0.x << 16) + w1_ * u2f((S).v1.x << 16) \
                + w2_ * u2f((S).v2.x << 16) + w3_ * u2f((S).v3.x << 16); \
      float hi_ = w0_ * u2f((S).v0.x & 0xffff0000u) + w1_ * u2f((S).v1.x & 0xffff0000u) \
                + w2_ * u2f((S).v2.x & 0xffff0000u) + w3_ * u2f((S).v3.x & 0xffff0000u); \
      o_.x = f2b(lo_) | (f2b(hi_) << 16); \
    } \
    { \
      float lo_ = w0_ * u2f((S).v0.y << 16) + w1_ * u2f((S).v1.y << 16) \
                + w2_ * u2f((S).v2.y << 16) + w3_ * u2f((S).v3.y << 16); \
      float hi_ = w0_ * u2f((S).v0.y & 0xffff0000u) + w1_ * u2f((S).v1.y & 0xffff0000u) \
                + w2_ * u2f((S).v2.y & 0xffff0000u) + w3_ * u2f((S).v3.y & 0xffff0000u); \
      o_.y = f2b(lo_) | (f2b(hi_) << 16); \
    } \
    *(uint2*)((bbuf) + bwr) = o_; \
  } while (0)

// stage A chunk (32KB): 512 thr x 4 x 16B linear copy of pre-swizzled image
#define STAGE_A(c, abuf) do { \
    const unsigned short* asrc_ = wp + (size_t)(c) * 16384 + t * 8; \
    _Pragma("unroll") for (int i_ = 0; i_ < 4; ++i_) \
      __builtin_amdgcn_global_load_lds( \
          (const __attribute__((address_space(1))) unsigned int*)(asrc_ + i_ * 4096), \
          (__attribute__((address_space(3))) unsigned int*)((abuf) + t * 16 + i_ * 8192), \
          16, 0, 0); \
  } while (0)

#define MFMA_STEP(abuf, bbuf) do { \
    _Pragma("unroll") for (int ks_ = 0; ks_ < 2; ++ks_) { \
      int kb_ = ks_ * 64 + kq; \
      bf16x8 a0_ = *(const bf16x8*)((abuf) + (wid * 32 + lm) * 128 + (kb_ ^ swz)); \
      bf16x8 a1_ = *(const bf16x8*)((abuf) + (wid * 32 + 16 + lm) * 128 + (kb_ ^ swz)); \
      bf16x8 b0_ = *(const bf16x8*)((bbuf) + lm * 128 + (kb_ ^ swz)); \
      bf16x8 b1_ = *(const bf16x8*)((bbuf) + (16 + lm) * 128 + (kb_ ^ swz)); \
      acc00 = __builtin_amdgcn_mfma_f32_16x16x32_bf16(a0_, b0_, acc00, 0, 0, 0); \
      acc01 = __builtin_amdgcn_mfma_f32_16x16x32_bf16(a0_, b1_, acc01, 0, 0, 0); \
      acc10 = __builtin_amdgcn_mfma_f32_16x16x32_bf16(a1_, b0_, acc10, 0, 0, 0); \
      acc11 = __builtin_amdgcn_mfma_f32_16x16x32_bf16(a1_, b1_, acc11, 0, 0, 0); \
    } \
  } while (0)

// PHASE2(c): consume chunks c,c+1; stage c+2,c+3; issue corners c+4,c+5; desc c+6,c+7;
// blend corners c+2,c+3 (issued last phase) -> B0,B1. Indices clamped at tail.
#define PHASE2(c, Sre, Sro, Sfe, Sfo, dvUe, dvUo, dvFe, dvFo) do { \
    MFMA_STEP(ldsA0, ldsB0); \
    MFMA_STEP(ldsA1, ldsB1); \
    asm volatile("s_waitcnt lgkmcnt(0)" ::: "memory"); \
    __builtin_amdgcn_s_barrier(); \
    { int c2_ = (c) + 2 < 36 ? (c) + 2 : 35; STAGE_A(c2_, ldsA0); } \
    { int c3_ = (c) + 3 < 36 ? (c) + 3 : 35; STAGE_A(c3_, ldsA1); } \
    { int c4_ = (c) + 4 < 36 ? (c) + 4 : 35; CORNERS(Sfe, dvUe, c4_); } \
    { int c5_ = (c) + 5 < 36 ? (c) + 5 : 35; CORNERS(Sfo, dvUo, c5_); } \
    { int c6_ = (c) + 6 < 36 ? (c) + 6 : 35; DESC_LD(c6_, dvFe); } \
    { int c7_ = (c) + 7 < 36 ? (c) + 7 : 35; DESC_LD(c7_, dvFo); } \
    BLEND(Sre, ldsB0); \
    BLEND(Sro, ldsB1); \
    asm volatile("s_waitcnt lgkmcnt(0)" ::: "memory"); \
    asm volatile("s_waitcnt vmcnt(10)" ::: "memory"); \
    __builtin_amdgcn_s_barrier(); \
  } while (0)

__global__ __launch_bounds__(512, 4) void k_deform_main(
    const unsigned short* __restrict__ xt, const unsigned short* __restrict__ wp,
    const char* __restrict__ desc, float* __restrict__ out) {
  __shared__ __align__(16) char lds[73728];  // A0,A1: 32KB; B0,B1: 4KB
  const int t = threadIdx.x;
  const int l = t & 63;
  const int wid = t >> 6;                    // 0..7 (32-row m-slice)

  int orig = blockIdx.x;
  int bid = (orig & 7) * 64 + (orig >> 3);   // XCD chunked swizzle (512%8==0)
  const int xh = bid & 1;
  const int rowid = bid >> 1;
  const int b = rowid >> 6;
  const int y = rowid & 63;

  const int p = t >> 4;              // local position 0..31
  const int cq = t & 15;             // channel quad (4 ch)
  const unsigned int cb8 = cq * 8;
  const int bwr = p * 128 + ((cq * 8) ^ ((p & 7) << 4));

  const int lm = l & 15;
  const int kq = (l >> 4) << 4;
  const int swz = (lm & 7) << 4;

  f32x4 acc00 = {}, acc01 = {}, acc10 = {}, acc11 = {};

  const char* descb = desc + (size_t)(b * 36 * 4096 + y * 64 + xh * 32 + p) * 16;
  const char* xtbB = (const char*)(xt + (size_t)b * 4096 * 256);

  char* ldsA0 = lds;
  char* ldsA1 = lds + 32768;
  char* ldsB0 = lds + 65536;
  char* ldsB1 = lds + 69632;

  CSet S0e, S0o, S1e, S1o;
  u32x4 dvAe, dvAo, dvBe, dvBo;

  // ---- prologue: A(0,1) staged+drained; B(0,1) built; corners(2,3) in flight; desc(4,5) held ----
  {
    u32x4 d0, d1, d2, d3;
    DESC_LD(0, d0);
    DESC_LD(1, d1);
    DESC_LD(2, d2);
    DESC_LD(3, d3);
    STAGE_A(0, ldsA0);
    STAGE_A(1, ldsA1);
    CSet St0, St1;
    CORNERS(St0, d0, 0);
    CORNERS(St1, d1, 1);
    BLEND(St0, ldsB0);               // implicit wait drains stage(0,1) too (older)
    BLEND(St1, ldsB1);
    CORNERS(S0e, d2, 2);             // stay in flight
    CORNERS(S0o, d3, 3);
    DESC_LD(4, dvAe);
    DESC_LD(5, dvAo);
    asm volatile("s_waitcnt lgkmcnt(0)" ::: "memory");
    __builtin_amdgcn_s_barrier();
  }

  // ---- 18 paired phases (9 x 2-rotation) ----
  for (int pr = 0; pr < 9; ++pr) {
    const int c = pr * 4;
    PHASE2(c,     S0e, S0o, S1e, S1o, dvAe, dvAo, dvBe, dvBo);
    PHASE2(c + 2, S1e, S1o, S0e, S0o, dvBe, dvBo, dvAe, dvAo);
  }

  // ---- epilogue: ReLU + fp32 store ----
  const int lm4 = (l >> 4) << 2;
  float* ob = out + (size_t)(b * 256 + wid * 32) * 4096 + y * 64 + xh * 32;
#pragma unroll
  for (int r = 0; r < 4; ++r) {
    ob[(size_t)(lm4 + r) * 4096 + lm] = fmaxf(acc00[r], 0.f);
    ob[(size_t)(lm4 + r) * 4096 + 16 + lm] = fmaxf(acc01[r], 0.f);
    ob[(size_t)(16 + lm4 + r) * 4096 + lm] = fmaxf(acc10[r], 0.f);
    ob[(size_t)(16 + lm4 + r) * 4096 + 16 + lm] = fmaxf(acc11[r], 0.f);
  }
}

extern "C" void kernel_launch(void* const* d_in, const int* in_sizes, int n_in,
                              void* d_out, int out_size, void* d_ws, size_t ws_size,
                              hipStream_t stream) {
  const float* x     = (const float*)d_in[0];
  const float* shape = (const float*)d_in[1];
  const float* w_off = (const float*)d_in[2];
  const float* w_def = (const float*)d_in[3];
  float* out = (float*)d_out;
  char* ws = (char*)d_ws;

  char* desc          = ws;                                          // 9,437,184 B
  unsigned short* xt  = (unsigned short*)(ws + 9437184);             // 8,388,608 B
  unsigned short* wpk = (unsigned short*)(ws + 9437184 + 8388608);   // 1,179,648 B

  k_prep<<<1856, 256, 0, stream>>>(shape, w_off, x, w_def, desc, xt, wpk);
  k_deform_main<<<512, 512, 0, stream>>>(xt, wpk, desc, out);
}

// Round 16
// 70.471 us; speedup vs baseline: 1.2776x; 1.0443x over previous
//
#include <hip/hip_runtime.h>
#include <hip/hip_bf16.h>
#include <stdint.h>

typedef __attribute__((ext_vector_type(8))) short bf16x8;
typedef __attribute__((ext_vector_type(4))) float f32x4;
typedef __attribute__((ext_vector_type(4))) unsigned int u32x4;

__device__ __forceinline__ float u2f(unsigned int u) {
  union { unsigned int i; float f; } c; c.i = u; return c.f;
}
__device__ __forceinline__ unsigned int f2b(float f) {
  union { float f; unsigned int i; } c; c.f = f;
  unsigned int x = c.i;
  return (x + 0x7fffu + ((x >> 16) & 1u)) >> 16;  // RNE to bf16
}
__device__ __forceinline__ unsigned int cvt_pk_bf16(float lo, float hi) {
  unsigned int r;
  asm("v_cvt_pk_bf16_f32 %0, %1, %2" : "=v"(r) : "v"(lo), "v"(hi));
  return r;  // lo -> bits[15:0], hi -> bits[31:16]
}

// ================= prep kernel (= R10/R13) =================
__global__ __launch_bounds__(256) void k_prep(
    const float* __restrict__ shape, const float* __restrict__ w_off,
    const float* __restrict__ x, const float* __restrict__ wd,
    char* __restrict__ desc, unsigned short* __restrict__ xt,
    unsigned short* __restrict__ wp) {
  __shared__ float tile[64][65];
  int bid = blockIdx.x;
  int t = threadIdx.x;
  if (bid < 576) {
    // ---- descriptors (16B): {u32 idx01 (two u16 pos idx), u32 idx23, u32 w01, u32 w23} ----
    int band = bid & 3;
    int rem = bid >> 2;                 // = b*36 + g*9 + kk
    int b = rem / 36, r2 = rem % 36, g = r2 / 9, kk = r2 % 9;
    int ky = kk / 3, kx = kk - ky * 3;
    int ocy = g * 18 + kk * 2;
    float wy[18], wx[18];
#pragma unroll
    for (int i = 0; i < 18; ++i) { wy[i] = w_off[ocy * 18 + i]; wx[i] = w_off[(ocy + 1) * 18 + i]; }
    const float* sp = shape + (size_t)b * 2 * 4096;
    char* dp = desc + (size_t)rem * 4096 * 16;
#pragma unroll
    for (int e = 0; e < 4; ++e) {
      int p = band * 1024 + t * 4 + e;
      int y = p >> 6, xx0 = p & 63;
      float dy = 0.f, dx = 0.f;
#pragma unroll
      for (int ic = 0; ic < 2; ++ic)
#pragma unroll
        for (int kyy = 0; kyy < 3; ++kyy) {
          int yy = y + kyy - 1;
          if (yy < 0 || yy > 63) continue;
#pragma unroll
          for (int kxx = 0; kxx < 3; ++kxx) {
            int xx = xx0 + kxx - 1;
            if (xx < 0 || xx > 63) continue;
            float sv = sp[ic * 4096 + yy * 64 + xx];
            dy += sv * wy[ic * 9 + kyy * 3 + kxx];
            dx += sv * wx[ic * 9 + kyy * 3 + kxx];
          }
        }
      float sy = dy + (float)(y + ky - 1);
      float sx = dx + (float)(xx0 + kx - 1);
      float fy = floorf(sy), fx = floorf(sx);
      float ly = sy - fy, lx = sx - fx;
      int y0 = (int)fy, x0 = (int)fx;
      float vy0 = (y0 >= 0 && y0 <= 63) ? 1.f : 0.f;
      float vy1 = (y0 >= -1 && y0 <= 62) ? 1.f : 0.f;
      float vx0 = (x0 >= 0 && x0 <= 63) ? 1.f : 0.f;
      float vx1 = (x0 >= -1 && x0 <= 62) ? 1.f : 0.f;
      float w00 = (1.f - ly) * (1.f - lx) * vy0 * vx0;
      float w01 = (1.f - ly) * lx * vy0 * vx1;
      float w10 = ly * (1.f - lx) * vy1 * vx0;
      float w11 = ly * lx * vy1 * vx1;
      unsigned int yc0 = (unsigned int)min(max(y0, 0), 63);
      unsigned int yc1 = (unsigned int)min(max(y0 + 1, 0), 63);
      unsigned int xc0 = (unsigned int)min(max(x0, 0), 63);
      unsigned int xc1 = (unsigned int)min(max(x0 + 1, 0), 63);
      u32x4 d;
      d[0] = (yc0 * 64 + xc0) | ((yc0 * 64 + xc1) << 16);
      d[1] = (yc1 * 64 + xc0) | ((yc1 * 64 + xc1) << 16);
      d[2] = f2b(w00) | (f2b(w01) << 16);
      d[3] = f2b(w10) | (f2b(w11) << 16);
      *(u32x4*)(dp + (size_t)p * 16) = d;
    }
  } else if (bid < 1600) {
    // ---- transpose ----
    int id = bid - 576;
    int b = id >> 8, ct = (id >> 6) & 3, pt = id & 63;
    int c0 = ct * 64, p0 = pt * 64;
#pragma unroll
    for (int i = 0; i < 4; ++i) {
      int row = (t >> 4) + i * 16;
      int seg = t & 15;
      float4 v = *(const float4*)&x[(size_t)(b * 256 + c0 + row) * 4096 + p0 + seg * 4];
      tile[row][seg * 4 + 0] = v.x;
      tile[row][seg * 4 + 1] = v.y;
      tile[row][seg * 4 + 2] = v.z;
      tile[row][seg * 4 + 3] = v.w;
    }
    __syncthreads();
    {
      int pl = t >> 2;
      int cs = (t & 3) * 16;
      unsigned int wbuf[8];
#pragma unroll
      for (int j = 0; j < 8; ++j)
        wbuf[j] = f2b(tile[cs + 2 * j][pl]) | (f2b(tile[cs + 2 * j + 1][pl]) << 16);
      unsigned short* dst = xt + (size_t)(b * 4096 + p0 + pl) * 256 + c0 + cs;
      *(u32x4*)(dst) = *(u32x4*)&wbuf[0];
      *(u32x4*)(dst + 8) = *(u32x4*)&wbuf[4];
    }
  } else {
    // ---- weight pack (SWIZZLED for linear global_load_lds staging) ----
    int id = (bid - 1600) * 256 + t;
    int m = id >> 8, ci = id & 255;
    int g = ci >> 6, c = ci & 63;
    int cs = c ^ ((m & 7) << 3);
    const float* src = wd + (size_t)(m * 256 + ci) * 9;
    float v[9];
#pragma unroll
    for (int kk = 0; kk < 9; ++kk) v[kk] = src[kk];
#pragma unroll
    for (int kk = 0; kk < 9; ++kk)
      wp[(size_t)(kk * 4 + g) * 16384 + m * 64 + cs] = (unsigned short)f2b(v[kk]);
  }
}

// ================= main fused kernel =================
// = R10 (best total, 69.9us) with ONE change: BLEND packs via v_cvt_pk_bf16_f32
// (1 inst for 2 f32->bf16 rounds, replaces ~14 VALU ops of manual RNE pack).
// grid 512: (b,y,xh); 512 thr (8 waves); tile M=256 x N=32; A LDS dbuf 2x32KB via
// global_load_lds (pre-swizzled); B dbuf 2x4KB. ONE barrier/phase:
// lgkmcnt(0)+vmcnt(5)+s_barrier — drains the 4 stage loads; corners+desc fly across.
struct CSet { uint2 v0, v1, v2, v3; unsigned int w01, w23; };

#define DESC_LD(c, dv) do { \
    dv = *(const u32x4*)(descb + (size_t)(((c) & 3) * 9 + ((c) >> 2)) * 65536); \
  } while (0)

#define CORNERS(S, dv, cc) do { \
    unsigned int base_ = (unsigned int)(((cc) & 3) << 7) + cb8; \
    (S).v0 = *(const uint2*)(xtbB + (((dv)[0] & 0xffffu) << 9) + base_); \
    (S).v1 = *(const uint2*)(xtbB + (((dv)[0] >> 16) << 9) + base_); \
    (S).v2 = *(const uint2*)(xtbB + (((dv)[1] & 0xffffu) << 9) + base_); \
    (S).v3 = *(const uint2*)(xtbB + (((dv)[1] >> 16) << 9) + base_); \
    (S).w01 = (dv)[2]; \
    (S).w23 = (dv)[3]; \
  } while (0)

#define BLEND(S, bbuf) do { \
    float w0_ = u2f((S).w01 << 16), w1_ = u2f((S).w01 & 0xffff0000u); \
    float w2_ = u2f((S).w23 << 16), w3_ = u2f((S).w23 & 0xffff0000u); \
    uint2 o_; \
    { \
      float lo_ = w0_ * u2f((S).v0.x << 16) + w1_ * u2f((S).v1.x << 16) \
                + w2_ * u2f((S).v2.x << 16) + w3_ * u2f((S).v3.x << 16); \
      float hi_ = w0_ * u2f((S).v0.x & 0xffff0000u) + w1_ * u2f((S).v1.x & 0xffff0000u) \
                + w2_ * u2f((S).v2.x & 0xffff0000u) + w3_ * u2f((S).v3.x & 0xffff0000u); \
      o_.x = cvt_pk_bf16(lo_, hi_); \
    } \
    { \
      float lo_ = w0_ * u2f((S).v0.y << 16) + w1_ * u2f((S).v1.y << 16) \
                + w2_ * u2f((S).v2.y << 16) + w3_ * u2f((S).v3.y << 16); \
      float hi_ = w0_ * u2f((S).v0.y & 0xffff0000u) + w1_ * u2f((S).v1.y & 0xffff0000u) \
                + w2_ * u2f((S).v2.y & 0xffff0000u) + w3_ * u2f((S).v3.y & 0xffff0000u); \
      o_.y = cvt_pk_bf16(lo_, hi_); \
    } \
    *(uint2*)((bbuf) + bwr) = o_; \
  } while (0)

// stage A chunk (32KB): 512 thr x 4 x 16B linear copy of pre-swizzled image
#define STAGE_A(c, abuf) do { \
    const unsigned short* asrc_ = wp + (size_t)(c) * 16384 + t * 8; \
    _Pragma("unroll") for (int i_ = 0; i_ < 4; ++i_) \
      __builtin_amdgcn_global_load_lds( \
          (const __attribute__((address_space(1))) unsigned int*)(asrc_ + i_ * 4096), \
          (__attribute__((address_space(3))) unsigned int*)((abuf) + t * 16 + i_ * 8192), \
          16, 0, 0); \
  } while (0)

#define MFMA_STEP(abuf, bbuf) do { \
    _Pragma("unroll") for (int ks_ = 0; ks_ < 2; ++ks_) { \
      int kb_ = ks_ * 64 + kq; \
      bf16x8 a0_ = *(const bf16x8*)((abuf) + (wid * 32 + lm) * 128 + (kb_ ^ swz)); \
      bf16x8 a1_ = *(const bf16x8*)((abuf) + (wid * 32 + 16 + lm) * 128 + (kb_ ^ swz)); \
      bf16x8 b0_ = *(const bf16x8*)((bbuf) + lm * 128 + (kb_ ^ swz)); \
      bf16x8 b1_ = *(const bf16x8*)((bbuf) + (16 + lm) * 128 + (kb_ ^ swz)); \
      acc00 = __builtin_amdgcn_mfma_f32_16x16x32_bf16(a0_, b0_, acc00, 0, 0, 0); \
      acc01 = __builtin_amdgcn_mfma_f32_16x16x32_bf16(a0_, b1_, acc01, 0, 0, 0); \
      acc10 = __builtin_amdgcn_mfma_f32_16x16x32_bf16(a1_, b0_, acc10, 0, 0, 0); \
      acc11 = __builtin_amdgcn_mfma_f32_16x16x32_bf16(a1_, b1_, acc11, 0, 0, 0); \
    } \
  } while (0)

// Phase(c): stage A(c+1)->other A buf; issue corners(c+2); load desc(c+3);
// MFMA A(c)xB(c); blend corners(c+1)->B(c+1); lgkm(0)+vmcnt(5)+barrier.
#define PHASE(c, Acur, Anext, Bcur, Bnext, Sfill, Sblend, dvUse, dvFill) do { \
    { int ca_ = (c) + 1 < 36 ? (c) + 1 : 35; STAGE_A(ca_, Anext); } \
    { int cc_ = (c) + 2 < 36 ? (c) + 2 : 35; CORNERS(Sfill, dvUse, cc_); } \
    { int cd_ = (c) + 3 < 36 ? (c) + 3 : 35; DESC_LD(cd_, dvFill); } \
    MFMA_STEP(Acur, Bcur); \
    BLEND(Sblend, Bnext); \
    asm volatile("s_waitcnt lgkmcnt(0)" ::: "memory"); \
    asm volatile("s_waitcnt vmcnt(5)" ::: "memory"); \
    __builtin_amdgcn_s_barrier(); \
  } while (0)

__global__ __launch_bounds__(512, 4) void k_deform_main(
    const unsigned short* __restrict__ xt, const unsigned short* __restrict__ wp,
    const char* __restrict__ desc, float* __restrict__ out) {
  __shared__ __align__(16) char lds[73728];  // A0,A1: 32KB; B0,B1: 4KB
  const int t = threadIdx.x;
  const int l = t & 63;
  const int wid = t >> 6;                    // 0..7 (32-row m-slice)

  int orig = blockIdx.x;
  int bid = (orig & 7) * 64 + (orig >> 3);   // XCD chunked swizzle (512%8==0)
  const int xh = bid & 1;
  const int rowid = bid >> 1;
  const int b = rowid >> 6;
  const int y = rowid & 63;

  const int p = t >> 4;              // local position 0..31
  const int cq = t & 15;             // channel quad (4 ch)
  const unsigned int cb8 = cq * 8;
  const int bwr = p * 128 + ((cq * 8) ^ ((p & 7) << 4));

  const int lm = l & 15;
  const int kq = (l >> 4) << 4;
  const int swz = (lm & 7) << 4;

  f32x4 acc00 = {}, acc01 = {}, acc10 = {}, acc11 = {};

  const char* descb = desc + (size_t)(b * 36 * 4096 + y * 64 + xh * 32 + p) * 16;
  const char* xtbB = (const char*)(xt + (size_t)b * 4096 * 256);

  char* ldsA0 = lds;
  char* ldsA1 = lds + 32768;
  char* ldsB0 = lds + 65536;
  char* ldsB1 = lds + 69632;

  CSet SE, SO;
  u32x4 dvA, dvB;

  // ---- prologue: A(0) staged+drained; B(0) built; SO=corners(1) flying; dvA=desc(2) ----
  {
    u32x4 d0, d1;
    DESC_LD(0, d0);
    DESC_LD(1, d1);
    DESC_LD(2, dvA);
    STAGE_A(0, ldsA0);
    CSet St;
    CORNERS(St, d0, 0);
    BLEND(St, ldsB0);                 // waits on St corners
    CORNERS(SO, d1, 1);               // stays in flight
    asm volatile("s_waitcnt lgkmcnt(0)" ::: "memory");
    asm volatile("s_waitcnt vmcnt(4)" ::: "memory");   // drain stage(0)+desc; keep SO
    __builtin_amdgcn_s_barrier();
  }

  // ---- 36 phases, 2-phase rotation ----
  for (int pr = 0; pr < 18; ++pr) {
    const int c = pr * 2;
    PHASE(c,     ldsA0, ldsA1, ldsB0, ldsB1, SE, SO, dvA, dvB);
    PHASE(c + 1, ldsA1, ldsA0, ldsB1, ldsB0, SO, SE, dvB, dvA);
  }

  // ---- epilogue: ReLU + fp32 store ----
  const int lm4 = (l >> 4) << 2;
  float* ob = out + (size_t)(b * 256 + wid * 32) * 4096 + y * 64 + xh * 32;
#pragma unroll
  for (int r = 0; r < 4; ++r) {
    ob[(size_t)(lm4 + r) * 4096 + lm] = fmaxf(acc00[r], 0.f);
    ob[(size_t)(lm4 + r) * 4096 + 16 + lm] = fmaxf(acc01[r], 0.f);
    ob[(size_t)(16 + lm4 + r) * 4096 + lm] = fmaxf(acc10[r], 0.f);
    ob[(size_t)(16 + lm4 + r) * 4096 + 16 + lm] = fmaxf(acc11[r], 0.f);
  }
}

extern "C" void kernel_launch(void* const* d_in, const int* in_sizes, int n_in,
                              void* d_out, int out_size, void* d_ws, size_t ws_size,
                              hipStream_t stream) {
  const float* x     = (const float*)d_in[0];
  const float* shape = (const float*)d_in[1];
  const float* w_off = (const float*)d_in[2];
  const float* w_def = (const float*)d_in[3];
  float* out = (float*)d_out;
  char* ws = (char*)d_ws;

  char* desc          = ws;                                          // 9,437,184 B
  unsigned short* xt  = (unsigned short*)(ws + 9437184);             // 8,388,608 B
  unsigned short* wpk = (unsigned short*)(ws + 9437184 + 8388608);   // 1,179,648 B

  k_prep<<<1856, 256, 0, stream>>>(shape, w_off, x, w_def, desc, xt, wpk);
  k_deform_main<<<512, 512, 0, stream>>>(xt, wpk, desc, out);
}